// Round 6
// baseline (2151.793 us; speedup 1.0000x reference)
//
#include <hip/hip_runtime.h>
#include <math.h>

#define LRELU_SLOPE 0.01f
#define BN_EPS 1e-5f

__device__ __forceinline__ float lrelu_f(float v) { return v >= 0.f ? v : LRELU_SLOPE * v; }

// ---------------------------------------------------------------------------
// Encoder / plain conv kernel, 2-row: thread = 4 co x 8 px x 2 rows.
// Block 256 = tile 16w x 16h x 64 co. MODE 0 plain, MODE 1 conv+lrelu+down2.
// Weights preloaded per-ci into 9 float4 regs (9 b128 amortized over 576 FMA).
// MODE1 input de-interleaved (even cols [0..16], odd [20..35], pitch 36).
// acc 64 + w 36 + row ~17 -> ~145 VGPR at (256,2): no spill.
// ---------------------------------------------------------------------------
template <int MODE, int CC, bool PARTIAL>
__global__ __launch_bounds__(256, 2) void conv3_kernel(
    const float* __restrict__ in, const float* __restrict__ wgt,
    const float* __restrict__ bias, float* __restrict__ out,
    int Cin, int Hin, int Win, int Cout, int Ho, int Wo, int apply_act,
    int segCi, int cogY, size_t seg_stride)
{
  constexpr int IH = (MODE == 1) ? 33 : 18;
  constexpr int IW = (MODE == 1) ? 33 : 18;
  constexpr int IP = (MODE == 1) ? 36 : 20;
  __shared__ __align__(16) float s_in[CC * IH * IP];
  __shared__ __align__(16) float s_w[CC * 9 * 64];

  const int tid = threadIdx.x;
  const int tx  = tid & 15;          // co group (4 co)
  const int ty  = tid >> 4;
  const int xh  = (ty & 1) * 8;      // 0 or 8
  const int rp  = ty >> 1;           // row pair 0..7 -> out rows 2rp, 2rp+1

  const int tilesX = Wo >> 4;
  const int x0   = (blockIdx.x % tilesX) * 16;
  const int y0   = (blockIdx.x / tilesX) * 16;
  const int cog0 = (blockIdx.y % cogY) * 64;
  const int seg  = blockIdx.y / cogY;
  const int ci_begin = seg * segCi;
  const int n    = blockIdx.z;
  if (PARTIAL) out += (size_t)seg * seg_stride;

  const size_t HWin = (size_t)Hin * Win;
  const float* inN = in + (size_t)n * Cin * HWin;

  float acc[4][2][8];
#pragma unroll
  for (int a = 0; a < 4; a++)
#pragma unroll
    for (int r = 0; r < 2; r++)
#pragma unroll
      for (int b = 0; b < 8; b++) acc[a][r][b] = 0.f;

  for (int ci0 = 0; ci0 < segCi; ci0 += CC) {
    const int chunk = (segCi - ci0 < CC) ? (segCi - ci0) : CC;
    __syncthreads();
    // ---- stage input tile ----
    const int tot = chunk * (IH * IW);
    for (int idx = tid; idx < tot; idx += 256) {
      const int ci  = idx / (IH * IW);
      const int rem = idx - ci * (IH * IW);
      const int r   = rem / IW;
      const int c   = rem - r * IW;
      float v = 0.f;
      const int gci = ci_begin + ci0 + ci;
      if (MODE == 1) {
        const int gy = 2 * y0 - 1 + r;
        const int gx = 2 * x0 - 1 + c;
        if (gy >= 0 && gy < Hin && gx >= 0 && gx < Win)
          v = inN[(size_t)gci * HWin + (size_t)gy * Win + gx];
        const int dst = (c & 1) ? (20 + (c >> 1)) : (c >> 1);  // de-interleave
        s_in[(ci * IH + r) * IP + dst] = v;
      } else {
        const int gy = y0 - 1 + r;
        const int gx = x0 - 1 + c;
        if (gy >= 0 && gy < Hin && gx >= 0 && gx < Win)
          v = inN[(size_t)gci * HWin + (size_t)gy * Win + gx];
        s_in[(ci * IH + r) * IP + c] = v;
      }
    }
    // ---- stage weights transposed: s_w[e*64 + co] ----
    const int e9 = chunk * 9;
    const int wtot = e9 * 64;
    for (int idx = tid; idx < wtot; idx += 256) {
      const int co = idx & 63;
      const int e  = idx >> 6;
      s_w[e * 64 + co] = wgt[(size_t)(cog0 + co) * Cin * 9 + (size_t)(ci_begin + ci0) * 9 + e];
    }
    __syncthreads();

    auto body = [&](int ci) {
      float4 wq[9];
#pragma unroll
      for (int t = 0; t < 9; t++)
        wq[t] = *(const float4*)&s_w[(ci * 9 + t) * 64 + (tx << 2)];
      if (MODE == 1) {
#pragma unroll
        for (int ir = 0; ir < 5; ir++) {           // input rows 4rp+0..4
          const int base = (ci * IH + 4 * rp + ir) * IP;
          const float4 ea = *(const float4*)&s_in[base + xh];
          const float4 eb = *(const float4*)&s_in[base + xh + 4];
          const float  e8 = s_in[base + xh + 8];
          const float4 oa = *(const float4*)&s_in[base + 20 + xh];
          const float4 ob = *(const float4*)&s_in[base + 24 + xh];
          const float ev[9] = {ea.x, ea.y, ea.z, ea.w, eb.x, eb.y, eb.z, eb.w, e8};
          const float ov[8] = {oa.x, oa.y, oa.z, oa.w, ob.x, ob.y, ob.z, ob.w};
#pragma unroll
          for (int r = 0; r < 2; r++) {
            const int ky = ir - 2 * r;
            if (ky < 0 || ky > 2) continue;
#pragma unroll
            for (int kx = 0; kx < 3; kx++) {
              const float4 w4 = wq[ky * 3 + kx];
              const float wv[4] = {w4.x, w4.y, w4.z, w4.w};
#pragma unroll
              for (int j = 0; j < 8; j++) {
                const float xv = (kx == 0) ? ev[j] : ((kx == 1) ? ov[j] : ev[j + 1]);
#pragma unroll
                for (int k = 0; k < 4; k++) acc[k][r][j] += wv[k] * xv;
              }
            }
          }
        }
      } else {
#pragma unroll
        for (int ir = 0; ir < 4; ir++) {           // input rows 2rp+0..3
          const int base = (ci * IH + 2 * rp + ir) * IP + xh;
          const float4 a4 = *(const float4*)&s_in[base];
          const float4 b4 = *(const float4*)&s_in[base + 4];
          const float2 c2 = *(const float2*)&s_in[base + 8];
          const float iv[10] = {a4.x, a4.y, a4.z, a4.w, b4.x, b4.y, b4.z, b4.w, c2.x, c2.y};
#pragma unroll
          for (int r = 0; r < 2; r++) {
            const int ky = ir - r;
            if (ky < 0 || ky > 2) continue;
#pragma unroll
            for (int kx = 0; kx < 3; kx++) {
              const float4 w4 = wq[ky * 3 + kx];
              const float wv[4] = {w4.x, w4.y, w4.z, w4.w};
#pragma unroll
              for (int j = 0; j < 8; j++) {
                const float xv = iv[j + kx];
#pragma unroll
                for (int k = 0; k < 4; k++) acc[k][r][j] += wv[k] * xv;
              }
            }
          }
        }
      }
    };
    if (chunk == CC) {
#pragma unroll
      for (int ci = 0; ci < CC; ci++) body(ci);
    } else {
      for (int ci = 0; ci < chunk; ci++) body(ci);  // d0 (Cin=3)
    }
  }

#pragma unroll
  for (int k = 0; k < 4; k++) {
    const int co = cog0 + tx * 4 + k;
    const float b = PARTIAL ? 0.f : bias[co];
#pragma unroll
    for (int r = 0; r < 2; r++) {
      float* op = out + ((size_t)((size_t)n * Cout + co) * Ho + (y0 + 2 * rp + r)) * Wo + x0 + xh;
      float4 v0, v1;
      v0.x = acc[k][r][0] + b; v0.y = acc[k][r][1] + b; v0.z = acc[k][r][2] + b; v0.w = acc[k][r][3] + b;
      v1.x = acc[k][r][4] + b; v1.y = acc[k][r][5] + b; v1.z = acc[k][r][6] + b; v1.w = acc[k][r][7] + b;
      if (!PARTIAL && apply_act) {
        v0.x = lrelu_f(v0.x); v0.y = lrelu_f(v0.y); v0.z = lrelu_f(v0.z); v0.w = lrelu_f(v0.w);
        v1.x = lrelu_f(v1.x); v1.y = lrelu_f(v1.y); v1.z = lrelu_f(v1.z); v1.w = lrelu_f(v1.w);
      }
      *reinterpret_cast<float4*>(op) = v0;
      *reinterpret_cast<float4*>(op + 4) = v1;
    }
  }
}

// ---------------------------------------------------------------------------
// Wide decoder kernel (u2/u3/u4): zero-insert up2 + conv3x3, parity-decomposed.
// Thread = 4 co x (8w x 4h px) = 4x2 quads; block tile 32w x 16h x 64 co.
// Per ci per wave: 9 b128 (w) + 3x(b128+b32) (iv) ~ 162 LDS cyc per 288 FMA.
// acc 128 -> (256,2) only (R3 lesson: tighter bound => scratch spill).
// ---------------------------------------------------------------------------
template <int CC, bool EPI, bool PARTIAL>
__global__ __launch_bounds__(256, 2) void up_wide_kernel(
    const float* __restrict__ in, const float* __restrict__ wgt,
    const float* __restrict__ bias, float* __restrict__ out,
    int Cin, int Hin, int Win, int Cout, int Ho, int Wo,
    int segCi, int cogY, size_t seg_stride,
    const float* __restrict__ w_ep, const float* __restrict__ b_ep)
{
  constexpr int IR = 9;    // staged input rows (16h out -> 8+1)
  constexpr int ICW = 17;  // staged input cols (32w out -> 16+1)
  constexpr int PC = 20;   // pitch
  __shared__ __align__(16) float s_in[CC * IR * PC];
  __shared__ __align__(16) float s_w[CC * 9 * 64];
  __shared__ float s_epi[EPI ? 3 * 16 * 33 : 1];

  const int tid = threadIdx.x;
  const int tx  = tid & 15;
  const int ty  = tid >> 4;
  const int qx0 = (ty & 3) * 4;   // first quad col (of 16)
  const int qy0 = (ty >> 2) * 2;  // first quad row (of 8)

  const int tilesX = Wo >> 5;
  const int x0   = (blockIdx.x % tilesX) * 32;
  const int y0   = (blockIdx.x / tilesX) * 16;
  const int cog0 = (blockIdx.y % cogY) * 64;
  const int seg  = blockIdx.y / cogY;
  const int ci_begin = seg * segCi;
  const int n    = blockIdx.z;
  if (PARTIAL) out += (size_t)seg * seg_stride;
  const int r0 = y0 >> 1;
  const int c0 = x0 >> 1;

  const size_t HWin = (size_t)Hin * Win;
  const float* inN = in + (size_t)n * Cin * HWin;

  float acc[4][4][8];
#pragma unroll
  for (int k = 0; k < 4; k++)
#pragma unroll
    for (int i = 0; i < 4; i++)
#pragma unroll
      for (int j = 0; j < 8; j++) acc[k][i][j] = 0.f;

  for (int ci0 = 0; ci0 < segCi; ci0 += CC) {
    __syncthreads();
    // ---- stage raw (non-zero-inserted) input tile, zero-pad hi edge ----
    const int tot = CC * (IR * ICW);
    for (int idx = tid; idx < tot; idx += 256) {
      const int ci  = idx / (IR * ICW);
      const int rem = idx - ci * (IR * ICW);
      const int r   = rem / ICW;
      const int c   = rem - r * ICW;
      const int gy = r0 + r, gx = c0 + c;
      float v = 0.f;
      if (gy < Hin && gx < Win)
        v = inN[(size_t)(ci_begin + ci0 + ci) * HWin + (size_t)gy * Win + gx];
      s_in[(ci * IR + r) * PC + c] = v;
    }
    // ---- stage weights transposed ----
    const int wtot = CC * 9 * 64;
    for (int idx = tid; idx < wtot; idx += 256) {
      const int co = idx & 63;
      const int e  = idx >> 6;
      s_w[e * 64 + co] = wgt[(size_t)(cog0 + co) * Cin * 9 + (size_t)(ci_begin + ci0) * 9 + e];
    }
    __syncthreads();

#pragma unroll
    for (int ci = 0; ci < CC; ci++) {
      float iv[3][5];
#pragma unroll
      for (int dr = 0; dr < 3; dr++) {
        const int base = (ci * IR + qy0 + dr) * PC + qx0;
        const float4 a4 = *(const float4*)&s_in[base];
        iv[dr][0] = a4.x; iv[dr][1] = a4.y; iv[dr][2] = a4.z; iv[dr][3] = a4.w;
        iv[dr][4] = s_in[base + 4];
      }
#pragma unroll
      for (int t = 0; t < 9; t++) {
        const int ky = t / 3, kx = t % 3;
        const float4 w4 = *(const float4*)&s_w[(ci * 9 + t) * 64 + (tx << 2)];
        const float wv[4] = {w4.x, w4.y, w4.z, w4.w};
        const int pr  = (ky == 1) ? 0 : 1;
        const int drr = (ky == 2) ? 1 : 0;
        const int pc  = (kx == 1) ? 0 : 1;
        const int dcc = (kx == 2) ? 1 : 0;
#pragma unroll
        for (int a = 0; a < 2; a++)
#pragma unroll
          for (int b = 0; b < 4; b++) {
            const float xv = iv[a + drr][b + dcc];
#pragma unroll
            for (int k = 0; k < 4; k++)
              acc[k][2 * a + pr][2 * b + pc] += wv[k] * xv;
          }
      }
    }
  }

  if (!EPI) {
#pragma unroll
    for (int k = 0; k < 4; k++) {
      const int co = cog0 + tx * 4 + k;
      const float bv = PARTIAL ? 0.f : bias[co];
#pragma unroll
      for (int i = 0; i < 4; i++) {
        const int y = y0 + 2 * qy0 + i;
        float* op = out + ((size_t)((size_t)n * Cout + co) * Ho + y) * Wo + x0 + 2 * qx0;
        float4 v0, v1;
        v0.x = acc[k][i][0] + bv; v0.y = acc[k][i][1] + bv; v0.z = acc[k][i][2] + bv; v0.w = acc[k][i][3] + bv;
        v1.x = acc[k][i][4] + bv; v1.y = acc[k][i][5] + bv; v1.z = acc[k][i][6] + bv; v1.w = acc[k][i][7] + bv;
        if (!PARTIAL) {
          v0.x = lrelu_f(v0.x); v0.y = lrelu_f(v0.y); v0.z = lrelu_f(v0.z); v0.w = lrelu_f(v0.w);
          v1.x = lrelu_f(v1.x); v1.y = lrelu_f(v1.y); v1.z = lrelu_f(v1.z); v1.w = lrelu_f(v1.w);
        }
        *reinterpret_cast<float4*>(op) = v0;
        *reinterpret_cast<float4*>(op + 4) = v1;
      }
    }
  } else {
    // ---- fused 1x1 (64->3): shfl-reduce over 16 co-lanes -> LDS -> float4 ----
    float wep[3][4];
#pragma unroll
    for (int o = 0; o < 3; o++)
#pragma unroll
      for (int k = 0; k < 4; k++) wep[o][k] = w_ep[o * 64 + tx * 4 + k];
    const float bv[4] = {bias[tx * 4 + 0], bias[tx * 4 + 1], bias[tx * 4 + 2], bias[tx * 4 + 3]};
    __syncthreads();
#pragma unroll
    for (int i = 0; i < 4; i++)
#pragma unroll
      for (int j = 0; j < 8; j++) {
        float h[4];
#pragma unroll
        for (int k = 0; k < 4; k++) h[k] = lrelu_f(acc[k][i][j] + bv[k]);
        float s0 = 0.f, s1 = 0.f, s2 = 0.f;
#pragma unroll
        for (int k = 0; k < 4; k++) {
          s0 += wep[0][k] * h[k]; s1 += wep[1][k] * h[k]; s2 += wep[2][k] * h[k];
        }
#pragma unroll
        for (int m = 1; m < 16; m <<= 1) {
          s0 += __shfl_xor(s0, m); s1 += __shfl_xor(s1, m); s2 += __shfl_xor(s2, m);
        }
        if (tx < 3) {
          const float sv = (tx == 0) ? s0 : ((tx == 1) ? s1 : s2);
          s_epi[tx * 528 + (2 * qy0 + i) * 33 + 2 * qx0 + j] = sv;
        }
      }
    __syncthreads();
    for (int idx = tid; idx < 384; idx += 256) {
      const int o   = idx >> 7;
      const int rem = idx & 127;
      const int row = rem >> 3;
      const int c4  = (rem & 7) << 2;
      const float be = b_ep[o];
      float4 v;
      v.x = s_epi[o * 528 + row * 33 + c4 + 0] + be;
      v.y = s_epi[o * 528 + row * 33 + c4 + 1] + be;
      v.z = s_epi[o * 528 + row * 33 + c4 + 2] + be;
      v.w = s_epi[o * 528 + row * 33 + c4 + 3] + be;
      float* op = out + ((size_t)((size_t)n * 3 + o) * Ho + (y0 + row)) * Wo + x0 + c4;
      *reinterpret_cast<float4*>(op) = v;
    }
  }
}

// ---------------------------------------------------------------------------
// Small-tile decoder kernel (u0/u1): NQ=2, T=16 (proven R4/R5 path).
// ---------------------------------------------------------------------------
template <int NQ, int KCO, int CC, bool EPI, bool PARTIAL>
__global__ __launch_bounds__(256, 2) void up_conv_kernel(
    const float* __restrict__ in, const float* __restrict__ wgt,
    const float* __restrict__ bias, float* __restrict__ out,
    int Cin, int Hin, int Win, int Cout, int Ho, int Wo,
    int segCi, int cogY, size_t seg_stride,
    const float* __restrict__ w_ep, const float* __restrict__ b_ep)
{
  constexpr int NCO = 16 * KCO;
  constexpr int LOG = (KCO == 4) ? 6 : 5;
  constexpr int TQ = 2 * NQ;
  constexpr int T  = 4 * TQ;
  constexpr int IR = 4 * NQ + 1;
  constexpr int PR = IR + 1;
  __shared__ __align__(16) float s_in[CC * IR * PR];
  __shared__ __align__(16) float s_w[CC * 9 * NCO];

  const int tid = threadIdx.x;
  const int tx  = tid & 15;
  const int ty  = tid >> 4;
  const int Qy  = ty >> 2;
  const int Qx  = ty & 3;

  const int tilesX = Wo / T;
  const int x0   = (blockIdx.x % tilesX) * T;
  const int y0   = (blockIdx.x / tilesX) * T;
  const int cog0 = (blockIdx.y % cogY) * NCO;
  const int seg  = blockIdx.y / cogY;
  const int ci_begin = seg * segCi;
  const int n    = blockIdx.z;
  if (PARTIAL) out += (size_t)seg * seg_stride;
  const int r0 = y0 >> 1;
  const int c0 = x0 >> 1;

  const size_t HWin = (size_t)Hin * Win;
  const float* inN = in + (size_t)n * Cin * HWin;

  float acc[KCO][TQ][TQ];
#pragma unroll
  for (int k = 0; k < KCO; k++)
#pragma unroll
    for (int i = 0; i < TQ; i++)
#pragma unroll
      for (int j = 0; j < TQ; j++) acc[k][i][j] = 0.f;

  for (int ci0 = 0; ci0 < segCi; ci0 += CC) {
    __syncthreads();
    const int tot = CC * (IR * IR);
    for (int idx = tid; idx < tot; idx += 256) {
      const int ci  = idx / (IR * IR);
      const int rem = idx - ci * (IR * IR);
      const int r   = rem / IR;
      const int c   = rem - r * IR;
      const int gy = r0 + r, gx = c0 + c;
      float v = 0.f;
      if (gy < Hin && gx < Win)
        v = inN[(size_t)(ci_begin + ci0 + ci) * HWin + (size_t)gy * Win + gx];
      s_in[(ci * IR + r) * PR + c] = v;
    }
    const int wtot = CC * 9 * NCO;
    for (int idx = tid; idx < wtot; idx += 256) {
      const int co = idx & (NCO - 1);
      const int e  = idx >> LOG;
      s_w[e * NCO + co] = wgt[(size_t)(cog0 + co) * Cin * 9 + (size_t)(ci_begin + ci0) * 9 + e];
    }
    __syncthreads();

#pragma unroll
    for (int ci = 0; ci < CC; ci++) {
      float iv[NQ + 1][NQ + 1];
#pragma unroll
      for (int dr = 0; dr <= NQ; dr++)
#pragma unroll
        for (int dc = 0; dc <= NQ; dc++)
          iv[dr][dc] = s_in[(ci * IR + NQ * Qy + dr) * PR + NQ * Qx + dc];
#pragma unroll
      for (int t = 0; t < 9; t++) {
        const int ky = t / 3, kx = t % 3;
        float wv[KCO];
        const float4 w4 = *(const float4*)&s_w[(ci * 9 + t) * 64 + (tx << 2)];
        wv[0] = w4.x; wv[1] = w4.y; wv[2] = w4.z; wv[3] = w4.w;
        const int pr  = (ky == 1) ? 0 : 1;
        const int drr = (ky == 2) ? 1 : 0;
        const int pc  = (kx == 1) ? 0 : 1;
        const int dcc = (kx == 2) ? 1 : 0;
#pragma unroll
        for (int a = 0; a < NQ; a++)
#pragma unroll
          for (int b = 0; b < NQ; b++) {
            const float xv = iv[a + drr][b + dcc];
#pragma unroll
            for (int k = 0; k < KCO; k++)
              acc[k][2 * a + pr][2 * b + pc] += wv[k] * xv;
          }
      }
    }
  }

#pragma unroll
  for (int k = 0; k < KCO; k++) {
    const int co = cog0 + tx * KCO + k;
    const float bv = PARTIAL ? 0.f : bias[co];
#pragma unroll
    for (int i = 0; i < TQ; i++) {
      const int y = y0 + TQ * Qy + i;
      float* op = out + ((size_t)((size_t)n * Cout + co) * Ho + y) * Wo + x0 + TQ * Qx;
      float4 v;
      if constexpr (PARTIAL) {
        v.x = acc[k][i][0]; v.y = acc[k][i][1]; v.z = acc[k][i][2]; v.w = acc[k][i][3];
      } else {
        v.x = lrelu_f(acc[k][i][0] + bv); v.y = lrelu_f(acc[k][i][1] + bv);
        v.z = lrelu_f(acc[k][i][2] + bv); v.w = lrelu_f(acc[k][i][3] + bv);
      }
      *reinterpret_cast<float4*>(op) = v;
    }
  }
}

// Sum K-split partials + bias (+lrelu), float4.
__global__ __launch_bounds__(256) void reduce_bias_act_kernel(
    float* __restrict__ dst, const float* __restrict__ part,
    const float* __restrict__ bias, int total4, int HW, int Cout,
    int S, int seg_stride4, int act)
{
  const int i = blockIdx.x * 256 + threadIdx.x;
  if (i >= total4) return;
  const float4* p = (const float4*)part;
  float4 s = p[i];
  for (int k = 1; k < S; k++) {
    const float4 v = p[i + (size_t)k * seg_stride4];
    s.x += v.x; s.y += v.y; s.z += v.z; s.w += v.w;
  }
  const int co = ((i << 2) / HW) % Cout;
  const float b = bias[co];
  s.x += b; s.y += b; s.z += b; s.w += b;
  if (act) { s.x = lrelu_f(s.x); s.y = lrelu_f(s.y); s.z = lrelu_f(s.z); s.w = lrelu_f(s.w); }
  ((float4*)dst)[i] = s;
}

// BatchNorm (batch stats) + LeakyReLU, in place. 1 block/channel.
__global__ __launch_bounds__(256) void bn_lrelu_kernel(
    float* __restrict__ h, const float* __restrict__ gamma, const float* __restrict__ beta)
{
  const int c = blockIdx.x;
  const int t = threadIdx.x;
  const size_t i0 = (size_t)c * 256 + t;
  const size_t i1 = (size_t)(1024 + c) * 256 + t;
  const float v0 = h[i0], v1 = h[i1];
  float s = v0 + v1;
  float q = v0 * v0 + v1 * v1;
  for (int o = 32; o > 0; o >>= 1) { s += __shfl_down(s, o); q += __shfl_down(q, o); }
  __shared__ float sh[8];
  __shared__ float param[2];
  const int wid = t >> 6, lane = t & 63;
  if (lane == 0) { sh[wid] = s; sh[4 + wid] = q; }
  __syncthreads();
  if (t == 0) {
    const float S = sh[0] + sh[1] + sh[2] + sh[3];
    const float Q = sh[4] + sh[5] + sh[6] + sh[7];
    const float mean = S * (1.f / 512.f);
    const float var = Q * (1.f / 512.f) - mean * mean;
    const float scale = gamma[c] / sqrtf(var + BN_EPS);
    param[0] = scale;
    param[1] = beta[c] - mean * scale;
  }
  __syncthreads();
  const float sc = param[0], sf = param[1];
  h[i0] = lrelu_f(v0 * sc + sf);
  h[i1] = lrelu_f(v1 * sc + sf);
}

extern "C" void kernel_launch(void* const* d_in, const int* in_sizes, int n_in,
                              void* d_out, int out_size, void* d_ws, size_t ws_size,
                              hipStream_t stream)
{
  (void)in_sizes; (void)n_in; (void)out_size; (void)ws_size;
  const float* x     = (const float*)d_in[0];
  const float* w_d0  = (const float*)d_in[1];
  const float* b_d0  = (const float*)d_in[2];
  const float* w_d1  = (const float*)d_in[3];
  const float* b_d1  = (const float*)d_in[4];
  const float* w_d2  = (const float*)d_in[5];
  const float* b_d2  = (const float*)d_in[6];
  const float* w_d3  = (const float*)d_in[7];
  const float* b_d3  = (const float*)d_in[8];
  const float* w_d4  = (const float*)d_in[9];
  const float* b_d4  = (const float*)d_in[10];
  const float* w_in  = (const float*)d_in[11];
  const float* b_in  = (const float*)d_in[12];
  const float* gamma = (const float*)d_in[13];
  const float* beta  = (const float*)d_in[14];
  const float* w_u0  = (const float*)d_in[15];
  const float* b_u0  = (const float*)d_in[16];
  const float* w_u1  = (const float*)d_in[17];
  const float* b_u1  = (const float*)d_in[18];
  const float* w_u2  = (const float*)d_in[19];
  const float* b_u2  = (const float*)d_in[20];
  const float* w_u3  = (const float*)d_in[21];
  const float* b_u3  = (const float*)d_in[22];
  const float* w_u4  = (const float*)d_in[23];
  const float* b_u4  = (const float*)d_in[24];
  const float* w_ep  = (const float*)d_in[25];
  const float* b_ep  = (const float*)d_in[26];

  // ---- 64 MiB workspace map (float offsets; 1 MiB = 262144 floats) ----
  float* W = (float*)d_ws;
  float* e0  = W;                   // [0,32)  d0 out
  float* e1  = W + 8388608;         // [32,48) d1 out
  float* Pd2 = W;                   // [0,32)  4 segs x 8 MiB
  float* e2  = W + 12582912;        // [48,56) d2 out
  float* Pd3 = W;                   // [0,32)  8 segs x 4 MiB
  float* e3  = W + 14680064;        // [56,58) d3 out
  float* Pd4 = W;                   // [0,32)  16 segs x 2 MiB
  float* e4  = W + 15204352;        // [58,60) d4 out
  float* Pin = W;                   // [0,32)  16 segs x 2 MiB
  float* Fb  = W + 15728640;        // [60,62) bn buffer
  float* Pu0 = W;                   // [0,32)  8 segs x 4 MiB
  float* G   = W + 8388608;         // [32,36) u0 out
  float* Pu1 = W;                   // [0,32)  4 segs x 8 MiB
  float* H   = W + 9437184;         // [36,44) u1 out
  float* Pu2 = W;                   // [0,32)  2 segs x 16 MiB
  float* I   = W + 11534336;        // [44,60) u2 out
  float* J   = W;                   // [0,32)  u3 out
  float* outp = (float*)d_out;

  const dim3 blk(256);
  // -------- encoder (conv+lrelu+down2 fused, 2-row tiles) --------
  conv3_kernel<1, 4, false><<<dim3(256,   1, 2), blk, 0, stream>>>(x,  w_d0, b_d0, e0,    3, 512, 512,   64, 256, 256, 1,   3,  1, 0);
  conv3_kernel<1, 8, false><<<dim3( 64,   2, 2), blk, 0, stream>>>(e0, w_d1, b_d1, e1,   64, 256, 256,  128, 128, 128, 1,  64,  2, 0);
  conv3_kernel<1, 8, true ><<<dim3( 16,  16, 2), blk, 0, stream>>>(e1, w_d2, b_d2, Pd2, 128, 128, 128,  256,  64,  64, 1,  32,  4, 2097152);
  reduce_bias_act_kernel<<<dim3(2048), blk, 0, stream>>>(e2, Pd2, b_d2, 524288, 4096, 256, 4, 524288, 1);
  conv3_kernel<1, 8, true ><<<dim3(  4,  64, 2), blk, 0, stream>>>(e2, w_d3, b_d3, Pd3, 256,  64,  64,  512,  32,  32, 1,  32,  8, 1048576);
  reduce_bias_act_kernel<<<dim3(1024), blk, 0, stream>>>(e3, Pd3, b_d3, 262144, 1024, 512, 8, 262144, 1);
  conv3_kernel<1, 8, true ><<<dim3(  1, 256, 2), blk, 0, stream>>>(e3, w_d4, b_d4, Pd4, 512,  32,  32, 1024,  16,  16, 1,  32, 16, 524288);
  reduce_bias_act_kernel<<<dim3( 512), blk, 0, stream>>>(e4, Pd4, b_d4, 131072, 256, 1024, 16, 131072, 1);
  // -------- innermost conv (no act) + BN + lrelu --------
  conv3_kernel<0, 8, true ><<<dim3(  1, 256, 2), blk, 0, stream>>>(e4, w_in, b_in, Pin, 1024, 16,  16, 1024,  16,  16, 0,  64, 16, 524288);
  reduce_bias_act_kernel<<<dim3( 512), blk, 0, stream>>>(Fb, Pin, b_in, 131072, 256, 1024, 16, 131072, 0);
  bn_lrelu_kernel<<<dim3(1024), blk, 0, stream>>>(Fb, gamma, beta);
  // -------- decoder --------
  up_conv_kernel<2, 4, 8, false, true ><<<dim3(  4, 64, 2), blk, 0, stream>>>(Fb, w_u0, b_u0, Pu0, 1024, 16,  16,  512,  32,  32, 128, 8, 1048576, nullptr, nullptr);
  reduce_bias_act_kernel<<<dim3(1024), blk, 0, stream>>>(G, Pu0, b_u0, 262144, 1024, 512, 8, 262144, 1);
  up_conv_kernel<2, 4, 8, false, true ><<<dim3( 16, 16, 2), blk, 0, stream>>>(G,  w_u1, b_u1, Pu1,  512, 32,  32,  256,  64,  64, 128, 4, 2097152, nullptr, nullptr);
  reduce_bias_act_kernel<<<dim3(2048), blk, 0, stream>>>(H, Pu1, b_u1, 524288, 4096, 256, 4, 524288, 1);
  up_wide_kernel<8, false, true ><<<dim3( 32,  4, 2), blk, 0, stream>>>(H,  w_u2, b_u2, Pu2,  256, 64,  64,  128, 128, 128, 128, 2, 4194304, nullptr, nullptr);
  reduce_bias_act_kernel<<<dim3(4096), blk, 0, stream>>>(I, Pu2, b_u2, 1048576, 16384, 128, 2, 1048576, 1);
  up_wide_kernel<8, false, false><<<dim3(128,  1, 2), blk, 0, stream>>>(I,  w_u3, b_u3, J,    128, 128, 128,   64, 256, 256, 128, 1, 0, nullptr, nullptr);
  // -------- u4 + fused 1x1 epilogue -> d_out --------
  up_wide_kernel<8, true,  false><<<dim3(512,  1, 2), blk, 0, stream>>>(J,  w_u4, b_u4, outp,  64, 256, 256,   64, 512, 512,  64, 1, 0, w_ep, b_ep);
}

// Round 7
// 2053.267 us; speedup vs baseline: 1.0480x; 1.0480x over previous
//
#include <hip/hip_runtime.h>
#include <math.h>

#define LRELU_SLOPE 0.01f
#define BN_EPS 1e-5f

// VGPR-cap law observed on this toolchain (R3/R4/R6 counters):
//   __launch_bounds__(256, N)  =>  VGPR cap ~= 256/N   (NOT 512/N!)
//   N=4 -> 64 (R3 spill), N=2 -> 128 (R6 spill of acc128 kernels), N=1 -> 256.
// Kernels with >100 live VGPRs MUST use N=1.

__device__ __forceinline__ float lrelu_f(float v) { return v >= 0.f ? v : LRELU_SLOPE * v; }

// ---------------------------------------------------------------------------
// Encoder / plain conv kernel, 2-row: thread = 4 co x 8 px x 2 rows.
// Block 256 = tile 16w x 16h x 64 co. MODE 0 plain, MODE 1 conv+lrelu+down2.
// Weights preloaded per-ci into 9 float4 regs (9 b128 amortized over 576 FMA).
// ~150 live VGPR -> (256,1).
// ---------------------------------------------------------------------------
template <int MODE, int CC, bool PARTIAL>
__global__ __launch_bounds__(256, 1) void conv3_kernel(
    const float* __restrict__ in, const float* __restrict__ wgt,
    const float* __restrict__ bias, float* __restrict__ out,
    int Cin, int Hin, int Win, int Cout, int Ho, int Wo, int apply_act,
    int segCi, int cogY, size_t seg_stride)
{
  constexpr int IH = (MODE == 1) ? 33 : 18;
  constexpr int IW = (MODE == 1) ? 33 : 18;
  constexpr int IP = (MODE == 1) ? 36 : 20;
  __shared__ __align__(16) float s_in[CC * IH * IP];
  __shared__ __align__(16) float s_w[CC * 9 * 64];

  const int tid = threadIdx.x;
  const int tx  = tid & 15;          // co group (4 co)
  const int ty  = tid >> 4;
  const int xh  = (ty & 1) * 8;      // 0 or 8
  const int rp  = ty >> 1;           // row pair 0..7 -> out rows 2rp, 2rp+1

  const int tilesX = Wo >> 4;
  const int x0   = (blockIdx.x % tilesX) * 16;
  const int y0   = (blockIdx.x / tilesX) * 16;
  const int cog0 = (blockIdx.y % cogY) * 64;
  const int seg  = blockIdx.y / cogY;
  const int ci_begin = seg * segCi;
  const int n    = blockIdx.z;
  if (PARTIAL) out += (size_t)seg * seg_stride;

  const size_t HWin = (size_t)Hin * Win;
  const float* inN = in + (size_t)n * Cin * HWin;

  float acc[4][2][8];
#pragma unroll
  for (int a = 0; a < 4; a++)
#pragma unroll
    for (int r = 0; r < 2; r++)
#pragma unroll
      for (int b = 0; b < 8; b++) acc[a][r][b] = 0.f;

  for (int ci0 = 0; ci0 < segCi; ci0 += CC) {
    const int chunk = (segCi - ci0 < CC) ? (segCi - ci0) : CC;
    __syncthreads();
    // ---- stage input tile ----
    const int tot = chunk * (IH * IW);
    for (int idx = tid; idx < tot; idx += 256) {
      const int ci  = idx / (IH * IW);
      const int rem = idx - ci * (IH * IW);
      const int r   = rem / IW;
      const int c   = rem - r * IW;
      float v = 0.f;
      const int gci = ci_begin + ci0 + ci;
      if (MODE == 1) {
        const int gy = 2 * y0 - 1 + r;
        const int gx = 2 * x0 - 1 + c;
        if (gy >= 0 && gy < Hin && gx >= 0 && gx < Win)
          v = inN[(size_t)gci * HWin + (size_t)gy * Win + gx];
        const int dst = (c & 1) ? (20 + (c >> 1)) : (c >> 1);  // de-interleave
        s_in[(ci * IH + r) * IP + dst] = v;
      } else {
        const int gy = y0 - 1 + r;
        const int gx = x0 - 1 + c;
        if (gy >= 0 && gy < Hin && gx >= 0 && gx < Win)
          v = inN[(size_t)gci * HWin + (size_t)gy * Win + gx];
        s_in[(ci * IH + r) * IP + c] = v;
      }
    }
    // ---- stage weights transposed: s_w[e*64 + co] ----
    const int e9 = chunk * 9;
    const int wtot = e9 * 64;
    for (int idx = tid; idx < wtot; idx += 256) {
      const int co = idx & 63;
      const int e  = idx >> 6;
      s_w[e * 64 + co] = wgt[(size_t)(cog0 + co) * Cin * 9 + (size_t)(ci_begin + ci0) * 9 + e];
    }
    __syncthreads();

    auto body = [&](int ci) {
      float4 wq[9];
#pragma unroll
      for (int t = 0; t < 9; t++)
        wq[t] = *(const float4*)&s_w[(ci * 9 + t) * 64 + (tx << 2)];
      if (MODE == 1) {
#pragma unroll
        for (int ir = 0; ir < 5; ir++) {           // input rows 4rp+0..4
          const int base = (ci * IH + 4 * rp + ir) * IP;
          const float4 ea = *(const float4*)&s_in[base + xh];
          const float4 eb = *(const float4*)&s_in[base + xh + 4];
          const float  e8 = s_in[base + xh + 8];
          const float4 oa = *(const float4*)&s_in[base + 20 + xh];
          const float4 ob = *(const float4*)&s_in[base + 24 + xh];
          const float ev[9] = {ea.x, ea.y, ea.z, ea.w, eb.x, eb.y, eb.z, eb.w, e8};
          const float ov[8] = {oa.x, oa.y, oa.z, oa.w, ob.x, ob.y, ob.z, ob.w};
#pragma unroll
          for (int r = 0; r < 2; r++) {
            const int ky = ir - 2 * r;
            if (ky < 0 || ky > 2) continue;
#pragma unroll
            for (int kx = 0; kx < 3; kx++) {
              const float4 w4 = wq[ky * 3 + kx];
              const float wv[4] = {w4.x, w4.y, w4.z, w4.w};
#pragma unroll
              for (int j = 0; j < 8; j++) {
                const float xv = (kx == 0) ? ev[j] : ((kx == 1) ? ov[j] : ev[j + 1]);
#pragma unroll
                for (int k = 0; k < 4; k++) acc[k][r][j] += wv[k] * xv;
              }
            }
          }
        }
      } else {
#pragma unroll
        for (int ir = 0; ir < 4; ir++) {           // input rows 2rp+0..3
          const int base = (ci * IH + 2 * rp + ir) * IP + xh;
          const float4 a4 = *(const float4*)&s_in[base];
          const float4 b4 = *(const float4*)&s_in[base + 4];
          const float2 c2 = *(const float2*)&s_in[base + 8];
          const float iv[10] = {a4.x, a4.y, a4.z, a4.w, b4.x, b4.y, b4.z, b4.w, c2.x, c2.y};
#pragma unroll
          for (int r = 0; r < 2; r++) {
            const int ky = ir - r;
            if (ky < 0 || ky > 2) continue;
#pragma unroll
            for (int kx = 0; kx < 3; kx++) {
              const float4 w4 = wq[ky * 3 + kx];
              const float wv[4] = {w4.x, w4.y, w4.z, w4.w};
#pragma unroll
              for (int j = 0; j < 8; j++) {
                const float xv = iv[j + kx];
#pragma unroll
                for (int k = 0; k < 4; k++) acc[k][r][j] += wv[k] * xv;
              }
            }
          }
        }
      }
    };
    if (chunk == CC) {
#pragma unroll
      for (int ci = 0; ci < CC; ci++) body(ci);
    } else {
      for (int ci = 0; ci < chunk; ci++) body(ci);  // d0 (Cin=3)
    }
  }

#pragma unroll
  for (int k = 0; k < 4; k++) {
    const int co = cog0 + tx * 4 + k;
    const float b = PARTIAL ? 0.f : bias[co];
#pragma unroll
    for (int r = 0; r < 2; r++) {
      float* op = out + ((size_t)((size_t)n * Cout + co) * Ho + (y0 + 2 * rp + r)) * Wo + x0 + xh;
      float4 v0, v1;
      v0.x = acc[k][r][0] + b; v0.y = acc[k][r][1] + b; v0.z = acc[k][r][2] + b; v0.w = acc[k][r][3] + b;
      v1.x = acc[k][r][4] + b; v1.y = acc[k][r][5] + b; v1.z = acc[k][r][6] + b; v1.w = acc[k][r][7] + b;
      if (!PARTIAL && apply_act) {
        v0.x = lrelu_f(v0.x); v0.y = lrelu_f(v0.y); v0.z = lrelu_f(v0.z); v0.w = lrelu_f(v0.w);
        v1.x = lrelu_f(v1.x); v1.y = lrelu_f(v1.y); v1.z = lrelu_f(v1.z); v1.w = lrelu_f(v1.w);
      }
      *reinterpret_cast<float4*>(op) = v0;
      *reinterpret_cast<float4*>(op + 4) = v1;
    }
  }
}

// ---------------------------------------------------------------------------
// Wide decoder kernel (u2/u3/u4): zero-insert up2 + conv3x3, parity-decomposed.
// Thread = 4 co x (8w x 4h px); block tile 32w x 16h x 64 co.
// Per ci per wave: ~162 LDS-pipe cyc per 288 FMA (144 CU cyc) -> near parity.
// acc 128 + ~50 temps ~ 180 VGPR -> (256,1) MANDATORY (cap law above).
// ---------------------------------------------------------------------------
template <int CC, bool EPI, bool PARTIAL>
__global__ __launch_bounds__(256, 1) void up_wide_kernel(
    const float* __restrict__ in, const float* __restrict__ wgt,
    const float* __restrict__ bias, float* __restrict__ out,
    int Cin, int Hin, int Win, int Cout, int Ho, int Wo,
    int segCi, int cogY, size_t seg_stride,
    const float* __restrict__ w_ep, const float* __restrict__ b_ep)
{
  constexpr int IR = 9;    // staged input rows (16h out -> 8+1)
  constexpr int ICW = 17;  // staged input cols (32w out -> 16+1)
  constexpr int PC = 20;   // pitch
  __shared__ __align__(16) float s_in[CC * IR * PC];
  __shared__ __align__(16) float s_w[CC * 9 * 64];
  __shared__ float s_epi[EPI ? 3 * 16 * 33 : 1];

  const int tid = threadIdx.x;
  const int tx  = tid & 15;
  const int ty  = tid >> 4;
  const int qx0 = (ty & 3) * 4;   // first quad col (of 16)
  const int qy0 = (ty >> 2) * 2;  // first quad row (of 8)

  const int tilesX = Wo >> 5;
  const int x0   = (blockIdx.x % tilesX) * 32;
  const int y0   = (blockIdx.x / tilesX) * 16;
  const int cog0 = (blockIdx.y % cogY) * 64;
  const int seg  = blockIdx.y / cogY;
  const int ci_begin = seg * segCi;
  const int n    = blockIdx.z;
  if (PARTIAL) out += (size_t)seg * seg_stride;
  const int r0 = y0 >> 1;
  const int c0 = x0 >> 1;

  const size_t HWin = (size_t)Hin * Win;
  const float* inN = in + (size_t)n * Cin * HWin;

  float acc[4][4][8];
#pragma unroll
  for (int k = 0; k < 4; k++)
#pragma unroll
    for (int i = 0; i < 4; i++)
#pragma unroll
      for (int j = 0; j < 8; j++) acc[k][i][j] = 0.f;

  for (int ci0 = 0; ci0 < segCi; ci0 += CC) {
    __syncthreads();
    // ---- stage raw (non-zero-inserted) input tile, zero-pad hi edge ----
    const int tot = CC * (IR * ICW);
    for (int idx = tid; idx < tot; idx += 256) {
      const int ci  = idx / (IR * ICW);
      const int rem = idx - ci * (IR * ICW);
      const int r   = rem / ICW;
      const int c   = rem - r * ICW;
      const int gy = r0 + r, gx = c0 + c;
      float v = 0.f;
      if (gy < Hin && gx < Win)
        v = inN[(size_t)(ci_begin + ci0 + ci) * HWin + (size_t)gy * Win + gx];
      s_in[(ci * IR + r) * PC + c] = v;
    }
    // ---- stage weights transposed ----
    const int wtot = CC * 9 * 64;
    for (int idx = tid; idx < wtot; idx += 256) {
      const int co = idx & 63;
      const int e  = idx >> 6;
      s_w[e * 64 + co] = wgt[(size_t)(cog0 + co) * Cin * 9 + (size_t)(ci_begin + ci0) * 9 + e];
    }
    __syncthreads();

#pragma unroll
    for (int ci = 0; ci < CC; ci++) {
      float iv[3][5];
#pragma unroll
      for (int dr = 0; dr < 3; dr++) {
        const int base = (ci * IR + qy0 + dr) * PC + qx0;
        const float4 a4 = *(const float4*)&s_in[base];
        iv[dr][0] = a4.x; iv[dr][1] = a4.y; iv[dr][2] = a4.z; iv[dr][3] = a4.w;
        iv[dr][4] = s_in[base + 4];
      }
#pragma unroll
      for (int t = 0; t < 9; t++) {
        const int ky = t / 3, kx = t % 3;
        const float4 w4 = *(const float4*)&s_w[(ci * 9 + t) * 64 + (tx << 2)];
        const float wv[4] = {w4.x, w4.y, w4.z, w4.w};
        const int pr  = (ky == 1) ? 0 : 1;
        const int drr = (ky == 2) ? 1 : 0;
        const int pc  = (kx == 1) ? 0 : 1;
        const int dcc = (kx == 2) ? 1 : 0;
#pragma unroll
        for (int a = 0; a < 2; a++)
#pragma unroll
          for (int b = 0; b < 4; b++) {
            const float xv = iv[a + drr][b + dcc];
#pragma unroll
            for (int k = 0; k < 4; k++)
              acc[k][2 * a + pr][2 * b + pc] += wv[k] * xv;
          }
      }
    }
  }

  if (!EPI) {
#pragma unroll
    for (int k = 0; k < 4; k++) {
      const int co = cog0 + tx * 4 + k;
      const float bv = PARTIAL ? 0.f : bias[co];
#pragma unroll
      for (int i = 0; i < 4; i++) {
        const int y = y0 + 2 * qy0 + i;
        float* op = out + ((size_t)((size_t)n * Cout + co) * Ho + y) * Wo + x0 + 2 * qx0;
        float4 v0, v1;
        v0.x = acc[k][i][0] + bv; v0.y = acc[k][i][1] + bv; v0.z = acc[k][i][2] + bv; v0.w = acc[k][i][3] + bv;
        v1.x = acc[k][i][4] + bv; v1.y = acc[k][i][5] + bv; v1.z = acc[k][i][6] + bv; v1.w = acc[k][i][7] + bv;
        if (!PARTIAL) {
          v0.x = lrelu_f(v0.x); v0.y = lrelu_f(v0.y); v0.z = lrelu_f(v0.z); v0.w = lrelu_f(v0.w);
          v1.x = lrelu_f(v1.x); v1.y = lrelu_f(v1.y); v1.z = lrelu_f(v1.z); v1.w = lrelu_f(v1.w);
        }
        *reinterpret_cast<float4*>(op) = v0;
        *reinterpret_cast<float4*>(op + 4) = v1;
      }
    }
  } else {
    // ---- fused 1x1 (64->3): shfl-reduce over 16 co-lanes -> LDS -> float4 ----
    float wep[3][4];
#pragma unroll
    for (int o = 0; o < 3; o++)
#pragma unroll
      for (int k = 0; k < 4; k++) wep[o][k] = w_ep[o * 64 + tx * 4 + k];
    const float bv[4] = {bias[tx * 4 + 0], bias[tx * 4 + 1], bias[tx * 4 + 2], bias[tx * 4 + 3]};
    __syncthreads();
#pragma unroll
    for (int i = 0; i < 4; i++)
#pragma unroll
      for (int j = 0; j < 8; j++) {
        float h[4];
#pragma unroll
        for (int k = 0; k < 4; k++) h[k] = lrelu_f(acc[k][i][j] + bv[k]);
        float s0 = 0.f, s1 = 0.f, s2 = 0.f;
#pragma unroll
        for (int k = 0; k < 4; k++) {
          s0 += wep[0][k] * h[k]; s1 += wep[1][k] * h[k]; s2 += wep[2][k] * h[k];
        }
#pragma unroll
        for (int m = 1; m < 16; m <<= 1) {
          s0 += __shfl_xor(s0, m); s1 += __shfl_xor(s1, m); s2 += __shfl_xor(s2, m);
        }
        if (tx < 3) {
          const float sv = (tx == 0) ? s0 : ((tx == 1) ? s1 : s2);
          s_epi[tx * 528 + (2 * qy0 + i) * 33 + 2 * qx0 + j] = sv;
        }
      }
    __syncthreads();
    for (int idx = tid; idx < 384; idx += 256) {
      const int o   = idx >> 7;
      const int rem = idx & 127;
      const int row = rem >> 3;
      const int c4  = (rem & 7) << 2;
      const float be = b_ep[o];
      float4 v;
      v.x = s_epi[o * 528 + row * 33 + c4 + 0] + be;
      v.y = s_epi[o * 528 + row * 33 + c4 + 1] + be;
      v.z = s_epi[o * 528 + row * 33 + c4 + 2] + be;
      v.w = s_epi[o * 528 + row * 33 + c4 + 3] + be;
      float* op = out + ((size_t)((size_t)n * 3 + o) * Ho + (y0 + row)) * Wo + x0 + c4;
      *reinterpret_cast<float4*>(op) = v;
    }
  }
}

// ---------------------------------------------------------------------------
// Small-tile decoder kernel (u0/u1): NQ=2, T=16. ~92 VGPR -> (256,2) ok.
// ---------------------------------------------------------------------------
template <int NQ, int KCO, int CC, bool EPI, bool PARTIAL>
__global__ __launch_bounds__(256, 2) void up_conv_kernel(
    const float* __restrict__ in, const float* __restrict__ wgt,
    const float* __restrict__ bias, float* __restrict__ out,
    int Cin, int Hin, int Win, int Cout, int Ho, int Wo,
    int segCi, int cogY, size_t seg_stride,
    const float* __restrict__ w_ep, const float* __restrict__ b_ep)
{
  constexpr int NCO = 16 * KCO;
  constexpr int LOG = (KCO == 4) ? 6 : 5;
  constexpr int TQ = 2 * NQ;
  constexpr int T  = 4 * TQ;
  constexpr int IR = 4 * NQ + 1;
  constexpr int PR = IR + 1;
  __shared__ __align__(16) float s_in[CC * IR * PR];
  __shared__ __align__(16) float s_w[CC * 9 * NCO];

  const int tid = threadIdx.x;
  const int tx  = tid & 15;
  const int ty  = tid >> 4;
  const int Qy  = ty >> 2;
  const int Qx  = ty & 3;

  const int tilesX = Wo / T;
  const int x0   = (blockIdx.x % tilesX) * T;
  const int y0   = (blockIdx.x / tilesX) * T;
  const int cog0 = (blockIdx.y % cogY) * NCO;
  const int seg  = blockIdx.y / cogY;
  const int ci_begin = seg * segCi;
  const int n    = blockIdx.z;
  if (PARTIAL) out += (size_t)seg * seg_stride;
  const int r0 = y0 >> 1;
  const int c0 = x0 >> 1;

  const size_t HWin = (size_t)Hin * Win;
  const float* inN = in + (size_t)n * Cin * HWin;

  float acc[KCO][TQ][TQ];
#pragma unroll
  for (int k = 0; k < KCO; k++)
#pragma unroll
    for (int i = 0; i < TQ; i++)
#pragma unroll
      for (int j = 0; j < TQ; j++) acc[k][i][j] = 0.f;

  for (int ci0 = 0; ci0 < segCi; ci0 += CC) {
    __syncthreads();
    const int tot = CC * (IR * IR);
    for (int idx = tid; idx < tot; idx += 256) {
      const int ci  = idx / (IR * IR);
      const int rem = idx - ci * (IR * IR);
      const int r   = rem / IR;
      const int c   = rem - r * IR;
      const int gy = r0 + r, gx = c0 + c;
      float v = 0.f;
      if (gy < Hin && gx < Win)
        v = inN[(size_t)(ci_begin + ci0 + ci) * HWin + (size_t)gy * Win + gx];
      s_in[(ci * IR + r) * PR + c] = v;
    }
    const int wtot = CC * 9 * NCO;
    for (int idx = tid; idx < wtot; idx += 256) {
      const int co = idx & (NCO - 1);
      const int e  = idx >> LOG;
      s_w[e * NCO + co] = wgt[(size_t)(cog0 + co) * Cin * 9 + (size_t)(ci_begin + ci0) * 9 + e];
    }
    __syncthreads();

#pragma unroll
    for (int ci = 0; ci < CC; ci++) {
      float iv[NQ + 1][NQ + 1];
#pragma unroll
      for (int dr = 0; dr <= NQ; dr++)
#pragma unroll
        for (int dc = 0; dc <= NQ; dc++)
          iv[dr][dc] = s_in[(ci * IR + NQ * Qy + dr) * PR + NQ * Qx + dc];
#pragma unroll
      for (int t = 0; t < 9; t++) {
        const int ky = t / 3, kx = t % 3;
        float wv[KCO];
        const float4 w4 = *(const float4*)&s_w[(ci * 9 + t) * 64 + (tx << 2)];
        wv[0] = w4.x; wv[1] = w4.y; wv[2] = w4.z; wv[3] = w4.w;
        const int pr  = (ky == 1) ? 0 : 1;
        const int drr = (ky == 2) ? 1 : 0;
        const int pc  = (kx == 1) ? 0 : 1;
        const int dcc = (kx == 2) ? 1 : 0;
#pragma unroll
        for (int a = 0; a < NQ; a++)
#pragma unroll
          for (int b = 0; b < NQ; b++) {
            const float xv = iv[a + drr][b + dcc];
#pragma unroll
            for (int k = 0; k < KCO; k++)
              acc[k][2 * a + pr][2 * b + pc] += wv[k] * xv;
          }
      }
    }
  }

#pragma unroll
  for (int k = 0; k < KCO; k++) {
    const int co = cog0 + tx * KCO + k;
    const float bv = PARTIAL ? 0.f : bias[co];
#pragma unroll
    for (int i = 0; i < TQ; i++) {
      const int y = y0 + TQ * Qy + i;
      float* op = out + ((size_t)((size_t)n * Cout + co) * Ho + y) * Wo + x0 + TQ * Qx;
      float4 v;
      if constexpr (PARTIAL) {
        v.x = acc[k][i][0]; v.y = acc[k][i][1]; v.z = acc[k][i][2]; v.w = acc[k][i][3];
      } else {
        v.x = lrelu_f(acc[k][i][0] + bv); v.y = lrelu_f(acc[k][i][1] + bv);
        v.z = lrelu_f(acc[k][i][2] + bv); v.w = lrelu_f(acc[k][i][3] + bv);
      }
      *reinterpret_cast<float4*>(op) = v;
    }
  }
}

// Sum K-split partials + bias (+lrelu), float4.
__global__ __launch_bounds__(256) void reduce_bias_act_kernel(
    float* __restrict__ dst, const float* __restrict__ part,
    const float* __restrict__ bias, int total4, int HW, int Cout,
    int S, int seg_stride4, int act)
{
  const int i = blockIdx.x * 256 + threadIdx.x;
  if (i >= total4) return;
  const float4* p = (const float4*)part;
  float4 s = p[i];
  for (int k = 1; k < S; k++) {
    const float4 v = p[i + (size_t)k * seg_stride4];
    s.x += v.x; s.y += v.y; s.z += v.z; s.w += v.w;
  }
  const int co = ((i << 2) / HW) % Cout;
  const float b = bias[co];
  s.x += b; s.y += b; s.z += b; s.w += b;
  if (act) { s.x = lrelu_f(s.x); s.y = lrelu_f(s.y); s.z = lrelu_f(s.z); s.w = lrelu_f(s.w); }
  ((float4*)dst)[i] = s;
}

// BatchNorm (batch stats) + LeakyReLU, in place. 1 block/channel.
__global__ __launch_bounds__(256) void bn_lrelu_kernel(
    float* __restrict__ h, const float* __restrict__ gamma, const float* __restrict__ beta)
{
  const int c = blockIdx.x;
  const int t = threadIdx.x;
  const size_t i0 = (size_t)c * 256 + t;
  const size_t i1 = (size_t)(1024 + c) * 256 + t;
  const float v0 = h[i0], v1 = h[i1];
  float s = v0 + v1;
  float q = v0 * v0 + v1 * v1;
  for (int o = 32; o > 0; o >>= 1) { s += __shfl_down(s, o); q += __shfl_down(q, o); }
  __shared__ float sh[8];
  __shared__ float param[2];
  const int wid = t >> 6, lane = t & 63;
  if (lane == 0) { sh[wid] = s; sh[4 + wid] = q; }
  __syncthreads();
  if (t == 0) {
    const float S = sh[0] + sh[1] + sh[2] + sh[3];
    const float Q = sh[4] + sh[5] + sh[6] + sh[7];
    const float mean = S * (1.f / 512.f);
    const float var = Q * (1.f / 512.f) - mean * mean;
    const float scale = gamma[c] / sqrtf(var + BN_EPS);
    param[0] = scale;
    param[1] = beta[c] - mean * scale;
  }
  __syncthreads();
  const float sc = param[0], sf = param[1];
  h[i0] = lrelu_f(v0 * sc + sf);
  h[i1] = lrelu_f(v1 * sc + sf);
}

extern "C" void kernel_launch(void* const* d_in, const int* in_sizes, int n_in,
                              void* d_out, int out_size, void* d_ws, size_t ws_size,
                              hipStream_t stream)
{
  (void)in_sizes; (void)n_in; (void)out_size; (void)ws_size;
  const float* x     = (const float*)d_in[0];
  const float* w_d0  = (const float*)d_in[1];
  const float* b_d0  = (const float*)d_in[2];
  const float* w_d1  = (const float*)d_in[3];
  const float* b_d1  = (const float*)d_in[4];
  const float* w_d2  = (const float*)d_in[5];
  const float* b_d2  = (const float*)d_in[6];
  const float* w_d3  = (const float*)d_in[7];
  const float* b_d3  = (const float*)d_in[8];
  const float* w_d4  = (const float*)d_in[9];
  const float* b_d4  = (const float*)d_in[10];
  const float* w_in  = (const float*)d_in[11];
  const float* b_in  = (const float*)d_in[12];
  const float* gamma = (const float*)d_in[13];
  const float* beta  = (const float*)d_in[14];
  const float* w_u0  = (const float*)d_in[15];
  const float* b_u0  = (const float*)d_in[16];
  const float* w_u1  = (const float*)d_in[17];
  const float* b_u1  = (const float*)d_in[18];
  const float* w_u2  = (const float*)d_in[19];
  const float* b_u2  = (const float*)d_in[20];
  const float* w_u3  = (const float*)d_in[21];
  const float* b_u3  = (const float*)d_in[22];
  const float* w_u4  = (const float*)d_in[23];
  const float* b_u4  = (const float*)d_in[24];
  const float* w_ep  = (const float*)d_in[25];
  const float* b_ep  = (const float*)d_in[26];

  // ---- 64 MiB workspace map (float offsets; 1 MiB = 262144 floats) ----
  float* W = (float*)d_ws;
  float* e0  = W;                   // [0,32)  d0 out
  float* e1  = W + 8388608;         // [32,48) d1 out
  float* Pd2 = W;                   // [0,32)  4 segs x 8 MiB
  float* e2  = W + 12582912;        // [48,56) d2 out
  float* Pd3 = W;                   // [0,32)  8 segs x 4 MiB
  float* e3  = W + 14680064;        // [56,58) d3 out
  float* Pd4 = W;                   // [0,32)  16 segs x 2 MiB
  float* e4  = W + 15204352;        // [58,60) d4 out
  float* Pin = W;                   // [0,32)  16 segs x 2 MiB
  float* Fb  = W + 15728640;        // [60,62) bn buffer
  float* Pu0 = W;                   // [0,32)  8 segs x 4 MiB
  float* G   = W + 8388608;         // [32,36) u0 out
  float* Pu1 = W;                   // [0,32)  4 segs x 8 MiB
  float* H   = W + 9437184;         // [36,44) u1 out
  float* Pu2 = W;                   // [0,32)  2 segs x 16 MiB
  float* I   = W + 11534336;        // [44,60) u2 out
  float* J   = W;                   // [0,32)  u3 out
  float* outp = (float*)d_out;

  const dim3 blk(256);
  // -------- encoder (conv+lrelu+down2 fused, 2-row tiles) --------
  conv3_kernel<1, 4, false><<<dim3(256,   1, 2), blk, 0, stream>>>(x,  w_d0, b_d0, e0,    3, 512, 512,   64, 256, 256, 1,   3,  1, 0);
  conv3_kernel<1, 8, false><<<dim3( 64,   2, 2), blk, 0, stream>>>(e0, w_d1, b_d1, e1,   64, 256, 256,  128, 128, 128, 1,  64,  2, 0);
  conv3_kernel<1, 8, true ><<<dim3( 16,  16, 2), blk, 0, stream>>>(e1, w_d2, b_d2, Pd2, 128, 128, 128,  256,  64,  64, 1,  32,  4, 2097152);
  reduce_bias_act_kernel<<<dim3(2048), blk, 0, stream>>>(e2, Pd2, b_d2, 524288, 4096, 256, 4, 524288, 1);
  conv3_kernel<1, 8, true ><<<dim3(  4,  64, 2), blk, 0, stream>>>(e2, w_d3, b_d3, Pd3, 256,  64,  64,  512,  32,  32, 1,  32,  8, 1048576);
  reduce_bias_act_kernel<<<dim3(1024), blk, 0, stream>>>(e3, Pd3, b_d3, 262144, 1024, 512, 8, 262144, 1);
  conv3_kernel<1, 8, true ><<<dim3(  1, 256, 2), blk, 0, stream>>>(e3, w_d4, b_d4, Pd4, 512,  32,  32, 1024,  16,  16, 1,  32, 16, 524288);
  reduce_bias_act_kernel<<<dim3( 512), blk, 0, stream>>>(e4, Pd4, b_d4, 131072, 256, 1024, 16, 131072, 1);
  // -------- innermost conv (no act) + BN + lrelu --------
  conv3_kernel<0, 8, true ><<<dim3(  1, 256, 2), blk, 0, stream>>>(e4, w_in, b_in, Pin, 1024, 16,  16, 1024,  16,  16, 0,  64, 16, 524288);
  reduce_bias_act_kernel<<<dim3( 512), blk, 0, stream>>>(Fb, Pin, b_in, 131072, 256, 1024, 16, 131072, 0);
  bn_lrelu_kernel<<<dim3(1024), blk, 0, stream>>>(Fb, gamma, beta);
  // -------- decoder --------
  up_conv_kernel<2, 4, 8, false, true ><<<dim3(  4, 64, 2), blk, 0, stream>>>(Fb, w_u0, b_u0, Pu0, 1024, 16,  16,  512,  32,  32, 128, 8, 1048576, nullptr, nullptr);
  reduce_bias_act_kernel<<<dim3(1024), blk, 0, stream>>>(G, Pu0, b_u0, 262144, 1024, 512, 8, 262144, 1);
  up_conv_kernel<2, 4, 8, false, true ><<<dim3( 16, 16, 2), blk, 0, stream>>>(G,  w_u1, b_u1, Pu1,  512, 32,  32,  256,  64,  64, 128, 4, 2097152, nullptr, nullptr);
  reduce_bias_act_kernel<<<dim3(2048), blk, 0, stream>>>(H, Pu1, b_u1, 524288, 4096, 256, 4, 524288, 1);
  up_wide_kernel<8, false, true ><<<dim3( 32,  4, 2), blk, 0, stream>>>(H,  w_u2, b_u2, Pu2,  256, 64,  64,  128, 128, 128, 128, 2, 4194304, nullptr, nullptr);
  reduce_bias_act_kernel<<<dim3(4096), blk, 0, stream>>>(I, Pu2, b_u2, 1048576, 16384, 128, 2, 1048576, 1);
  up_wide_kernel<8, false, false><<<dim3(128,  1, 2), blk, 0, stream>>>(I,  w_u3, b_u3, J,    128, 128, 128,   64, 256, 256, 128, 1, 0, nullptr, nullptr);
  // -------- u4 + fused 1x1 epilogue -> d_out --------
  up_wide_kernel<8, true,  false><<<dim3(512,  1, 2), blk, 0, stream>>>(J,  w_u4, b_u4, outp,  64, 256, 256,   64, 512, 512,  64, 1, 0, w_ep, b_ep);
}

// Round 8
// 1724.781 us; speedup vs baseline: 1.2476x; 1.1905x over previous
//
#include <hip/hip_runtime.h>
#include <math.h>

#define LRELU_SLOPE 0.01f
#define BN_EPS 1e-5f

// VGPR/occupancy law measured on this toolchain (R3/R6/R7 counters + m69):
//   waves/SIMD steps at VGPR {64,128,256}: <=64 -> 8, <=128 -> 4, <=256 -> 2.
//   __launch_bounds__(256,4) caps at 64 (R3 spill), (256,2) at 128 (R6 spill),
//   (256,1) at 256 but >128 VGPR kernels drop to 2 waves/SIMD and go
//   latency-bound (R7: VALUBusy 36%). Sweet spot: ~92 VGPR at (256,2).

__device__ __forceinline__ float lrelu_f(float v) { return v >= 0.f ? v : LRELU_SLOPE * v; }

// ---------------------------------------------------------------------------
// Encoder / plain conv kernel, 8-wide: thread = 4 co x 8 px (one row).
// Block 256 = tile 16w x 8h x 64 co. MODE 0 plain, MODE 1 conv+lrelu+down2.
// MODE1 input staged de-interleaved: even cols [0..16], odd cols [20..35],
// pitch 36. ~92 VGPR at (256,2) -> 4 waves/SIMD (R5-measured best).
// ---------------------------------------------------------------------------
template <int MODE, int CC, bool PARTIAL>
__global__ __launch_bounds__(256, 2) void conv3_kernel(
    const float* __restrict__ in, const float* __restrict__ wgt,
    const float* __restrict__ bias, float* __restrict__ out,
    int Cin, int Hin, int Win, int Cout, int Ho, int Wo, int apply_act,
    int segCi, int cogY, size_t seg_stride)
{
  constexpr int IH = (MODE == 1) ? 17 : 10;
  constexpr int IW = (MODE == 1) ? 33 : 18;
  constexpr int IP = (MODE == 1) ? 36 : 20;
  __shared__ __align__(16) float s_in[CC * IH * IP];
  __shared__ __align__(16) float s_w[CC * 9 * 64];

  const int tid = threadIdx.x;
  const int tx  = tid & 15;          // co group (4 co)
  const int ty  = tid >> 4;
  const int row = ty >> 1;           // 0..7
  const int xh  = (ty & 1) * 8;      // 0 or 8

  const int tilesX = Wo >> 4;
  const int x0   = (blockIdx.x % tilesX) * 16;
  const int y0   = (blockIdx.x / tilesX) * 8;
  const int cog0 = (blockIdx.y % cogY) * 64;
  const int seg  = blockIdx.y / cogY;
  const int ci_begin = seg * segCi;
  const int n    = blockIdx.z;
  if (PARTIAL) out += (size_t)seg * seg_stride;

  const size_t HWin = (size_t)Hin * Win;
  const float* inN = in + (size_t)n * Cin * HWin;

  float acc[4][8];
#pragma unroll
  for (int a = 0; a < 4; a++)
#pragma unroll
    for (int b = 0; b < 8; b++) acc[a][b] = 0.f;

  for (int ci0 = 0; ci0 < segCi; ci0 += CC) {
    const int chunk = (segCi - ci0 < CC) ? (segCi - ci0) : CC;
    __syncthreads();
    // ---- stage input tile ----
    const int tot = chunk * (IH * IW);
    for (int idx = tid; idx < tot; idx += 256) {
      const int ci  = idx / (IH * IW);
      const int rem = idx - ci * (IH * IW);
      const int r   = rem / IW;
      const int c   = rem - r * IW;
      float v = 0.f;
      const int gci = ci_begin + ci0 + ci;
      if (MODE == 1) {
        const int gy = 2 * y0 - 1 + r;
        const int gx = 2 * x0 - 1 + c;
        if (gy >= 0 && gy < Hin && gx >= 0 && gx < Win)
          v = inN[(size_t)gci * HWin + (size_t)gy * Win + gx];
        const int dst = (c & 1) ? (20 + (c >> 1)) : (c >> 1);  // de-interleave
        s_in[(ci * IH + r) * IP + dst] = v;
      } else {
        const int gy = y0 - 1 + r;
        const int gx = x0 - 1 + c;
        if (gy >= 0 && gy < Hin && gx >= 0 && gx < Win)
          v = inN[(size_t)gci * HWin + (size_t)gy * Win + gx];
        s_in[(ci * IH + r) * IP + c] = v;
      }
    }
    // ---- stage weights transposed: s_w[e*64 + co] ----
    const int e9 = chunk * 9;
    const int wtot = e9 * 64;
    for (int idx = tid; idx < wtot; idx += 256) {
      const int co = idx & 63;
      const int e  = idx >> 6;
      s_w[e * 64 + co] = wgt[(size_t)(cog0 + co) * Cin * 9 + (size_t)(ci_begin + ci0) * 9 + e];
    }
    __syncthreads();

    auto body = [&](int ci) {
#pragma unroll
      for (int ky = 0; ky < 3; ky++) {
        if (MODE == 1) {
          const int base = (ci * IH + 2 * row + ky) * IP;
          const float4 ea = *(const float4*)&s_in[base + xh];
          const float4 eb = *(const float4*)&s_in[base + xh + 4];
          const float  e8 = s_in[base + xh + 8];
          const float4 oa = *(const float4*)&s_in[base + 20 + xh];
          const float4 ob = *(const float4*)&s_in[base + 24 + xh];
          const float ev[9] = {ea.x, ea.y, ea.z, ea.w, eb.x, eb.y, eb.z, eb.w, e8};
          const float ov[8] = {oa.x, oa.y, oa.z, oa.w, ob.x, ob.y, ob.z, ob.w};
#pragma unroll
          for (int kx = 0; kx < 3; kx++) {
            const int e = ci * 9 + ky * 3 + kx;
            const float4 w4 = *(const float4*)&s_w[e * 64 + (tx << 2)];
            const float wv[4] = {w4.x, w4.y, w4.z, w4.w};
#pragma unroll
            for (int j = 0; j < 8; j++) {
              const float xv = (kx == 0) ? ev[j] : ((kx == 1) ? ov[j] : ev[j + 1]);
#pragma unroll
              for (int k = 0; k < 4; k++) acc[k][j] += wv[k] * xv;
            }
          }
        } else {
          const int base = (ci * IH + row + ky) * IP + xh;
          const float4 a4 = *(const float4*)&s_in[base];
          const float4 b4 = *(const float4*)&s_in[base + 4];
          const float2 c2 = *(const float2*)&s_in[base + 8];
          const float iv[10] = {a4.x, a4.y, a4.z, a4.w, b4.x, b4.y, b4.z, b4.w, c2.x, c2.y};
#pragma unroll
          for (int kx = 0; kx < 3; kx++) {
            const int e = ci * 9 + ky * 3 + kx;
            const float4 w4 = *(const float4*)&s_w[e * 64 + (tx << 2)];
            const float wv[4] = {w4.x, w4.y, w4.z, w4.w};
#pragma unroll
            for (int j = 0; j < 8; j++) {
              const float xv = iv[j + kx];
#pragma unroll
              for (int k = 0; k < 4; k++) acc[k][j] += wv[k] * xv;
            }
          }
        }
      }
    };
    if (chunk == CC) {
#pragma unroll
      for (int ci = 0; ci < CC; ci++) body(ci);
    } else {
      for (int ci = 0; ci < chunk; ci++) body(ci);  // d0 (Cin=3)
    }
  }

#pragma unroll
  for (int k = 0; k < 4; k++) {
    const int co = cog0 + tx * 4 + k;
    float* op = out + ((size_t)((size_t)n * Cout + co) * Ho + (y0 + row)) * Wo + x0 + xh;
    float4 v0, v1;
    if constexpr (PARTIAL) {
      v0.x = acc[k][0]; v0.y = acc[k][1]; v0.z = acc[k][2]; v0.w = acc[k][3];
      v1.x = acc[k][4]; v1.y = acc[k][5]; v1.z = acc[k][6]; v1.w = acc[k][7];
    } else {
      const float b = bias[co];
      v0.x = acc[k][0] + b; v0.y = acc[k][1] + b; v0.z = acc[k][2] + b; v0.w = acc[k][3] + b;
      v1.x = acc[k][4] + b; v1.y = acc[k][5] + b; v1.z = acc[k][6] + b; v1.w = acc[k][7] + b;
      if (apply_act) {
        v0.x = lrelu_f(v0.x); v0.y = lrelu_f(v0.y); v0.z = lrelu_f(v0.z); v0.w = lrelu_f(v0.w);
        v1.x = lrelu_f(v1.x); v1.y = lrelu_f(v1.y); v1.z = lrelu_f(v1.z); v1.w = lrelu_f(v1.w);
      }
    }
    *reinterpret_cast<float4*>(op) = v0;
    *reinterpret_cast<float4*>(op + 4) = v1;
  }
}

// ---------------------------------------------------------------------------
// Decoder kernel: zero-insert up2 + conv3x3 (+lrelu), parity-decomposed.
// NQ=2: thread = 4co x 4x4 px (2x2 quads), tile 16x16 x 64co. ~92 VGPR at
// (256,2) -> 4 waves/SIMD (R5-measured best: u4 = 238 us).
// R8 delta: iv row loads vectorized (float2+float; row base is always even).
// ---------------------------------------------------------------------------
template <int NQ, int KCO, int CC, bool EPI, bool PARTIAL>
__global__ __launch_bounds__(256, 2) void up_conv_kernel(
    const float* __restrict__ in, const float* __restrict__ wgt,
    const float* __restrict__ bias, float* __restrict__ out,
    int Cin, int Hin, int Win, int Cout, int Ho, int Wo,
    int segCi, int cogY, size_t seg_stride,
    const float* __restrict__ w_ep, const float* __restrict__ b_ep)
{
  constexpr int NCO = 16 * KCO;
  constexpr int LOG = (KCO == 4) ? 6 : 5;
  constexpr int TQ = 2 * NQ;
  constexpr int T  = 4 * TQ;
  constexpr int IR = 4 * NQ + 1;
  constexpr int PR = IR + 1;
  __shared__ __align__(16) float s_in[CC * IR * PR];
  __shared__ __align__(16) float s_w[CC * 9 * NCO];
  __shared__ float s_epi[EPI ? 3 * 16 * 17 : 1];

  const int tid = threadIdx.x;
  const int tx  = tid & 15;
  const int ty  = tid >> 4;
  const int Qy  = ty >> 2;
  const int Qx  = ty & 3;

  const int tilesX = Wo / T;
  const int x0   = (blockIdx.x % tilesX) * T;
  const int y0   = (blockIdx.x / tilesX) * T;
  const int cog0 = (blockIdx.y % cogY) * NCO;
  const int seg  = blockIdx.y / cogY;
  const int ci_begin = seg * segCi;
  const int n    = blockIdx.z;
  if (PARTIAL) out += (size_t)seg * seg_stride;
  const int r0 = y0 >> 1;
  const int c0 = x0 >> 1;

  const size_t HWin = (size_t)Hin * Win;
  const float* inN = in + (size_t)n * Cin * HWin;

  float acc[KCO][TQ][TQ];
#pragma unroll
  for (int k = 0; k < KCO; k++)
#pragma unroll
    for (int i = 0; i < TQ; i++)
#pragma unroll
      for (int j = 0; j < TQ; j++) acc[k][i][j] = 0.f;

  for (int ci0 = 0; ci0 < segCi; ci0 += CC) {
    __syncthreads();
    // ---- stage raw (non-zero-inserted) input tile, zero-pad hi edge ----
    const int tot = CC * (IR * IR);
    for (int idx = tid; idx < tot; idx += 256) {
      const int ci  = idx / (IR * IR);
      const int rem = idx - ci * (IR * IR);
      const int r   = rem / IR;
      const int c   = rem - r * IR;
      const int gy = r0 + r, gx = c0 + c;
      float v = 0.f;
      if (gy < Hin && gx < Win)
        v = inN[(size_t)(ci_begin + ci0 + ci) * HWin + (size_t)gy * Win + gx];
      s_in[(ci * IR + r) * PR + c] = v;
    }
    // ---- stage weights transposed ----
    const int wtot = CC * 9 * NCO;
    for (int idx = tid; idx < wtot; idx += 256) {
      const int co = idx & (NCO - 1);
      const int e  = idx >> LOG;
      s_w[e * NCO + co] = wgt[(size_t)(cog0 + co) * Cin * 9 + (size_t)(ci_begin + ci0) * 9 + e];
    }
    __syncthreads();

#pragma unroll
    for (int ci = 0; ci < CC; ci++) {
      // iv rows: base = (..)*PR + 2*Qx is even -> float2 + scalar (6 LDS ops vs 9)
      float iv[NQ + 1][NQ + 1];
#pragma unroll
      for (int dr = 0; dr <= NQ; dr++) {
        const int base = (ci * IR + NQ * Qy + dr) * PR + NQ * Qx;
        if constexpr (NQ == 2) {
          const float2 p = *(const float2*)&s_in[base];
          iv[dr][0] = p.x; iv[dr][1] = p.y; iv[dr][2] = s_in[base + 2];
        } else {
#pragma unroll
          for (int dc = 0; dc <= NQ; dc++) iv[dr][dc] = s_in[base + dc];
        }
      }
#pragma unroll
      for (int t = 0; t < 9; t++) {
        const int ky = t / 3, kx = t % 3;
        float wv[KCO];
        const float4 w4 = *(const float4*)&s_w[(ci * 9 + t) * 64 + (tx << 2)];
        wv[0] = w4.x; wv[1] = w4.y; wv[2] = w4.z; wv[3] = w4.w;
        const int pr  = (ky == 1) ? 0 : 1;
        const int drr = (ky == 2) ? 1 : 0;
        const int pc  = (kx == 1) ? 0 : 1;
        const int dcc = (kx == 2) ? 1 : 0;
#pragma unroll
        for (int a = 0; a < NQ; a++)
#pragma unroll
          for (int b = 0; b < NQ; b++) {
            const float xv = iv[a + drr][b + dcc];
#pragma unroll
            for (int k = 0; k < KCO; k++)
              acc[k][2 * a + pr][2 * b + pc] += wv[k] * xv;
          }
      }
    }
  }

  if (!EPI) {
#pragma unroll
    for (int k = 0; k < KCO; k++) {
      const int co = cog0 + tx * KCO + k;
      const float bv = PARTIAL ? 0.f : bias[co];
#pragma unroll
      for (int i = 0; i < TQ; i++) {
        const int y = y0 + TQ * Qy + i;
        float* op = out + ((size_t)((size_t)n * Cout + co) * Ho + y) * Wo + x0 + TQ * Qx;
        float4 v;
        if constexpr (PARTIAL) {
          v.x = acc[k][i][0]; v.y = acc[k][i][1]; v.z = acc[k][i][2]; v.w = acc[k][i][3];
        } else {
          v.x = lrelu_f(acc[k][i][0] + bv); v.y = lrelu_f(acc[k][i][1] + bv);
          v.z = lrelu_f(acc[k][i][2] + bv); v.w = lrelu_f(acc[k][i][3] + bv);
        }
        *reinterpret_cast<float4*>(op) = v;
      }
    }
  } else {
    // ---- fused 1x1 (64->3): shfl-reduce over 16 co-lanes -> LDS -> float4 ----
    float wep[3][KCO];
#pragma unroll
    for (int o = 0; o < 3; o++)
#pragma unroll
      for (int k = 0; k < KCO; k++) wep[o][k] = w_ep[o * 64 + tx * KCO + k];
    const float bv[KCO] = {bias[tx * KCO + 0], bias[tx * KCO + 1],
                           bias[tx * KCO + 2], bias[tx * KCO + 3]};
    __syncthreads();
#pragma unroll
    for (int i = 0; i < TQ; i++)
#pragma unroll
      for (int j = 0; j < TQ; j++) {
        float h[KCO];
#pragma unroll
        for (int k = 0; k < KCO; k++) h[k] = lrelu_f(acc[k][i][j] + bv[k]);
        float s0 = 0.f, s1 = 0.f, s2 = 0.f;
#pragma unroll
        for (int k = 0; k < KCO; k++) {
          s0 += wep[0][k] * h[k]; s1 += wep[1][k] * h[k]; s2 += wep[2][k] * h[k];
        }
#pragma unroll
        for (int m = 1; m < 16; m <<= 1) {
          s0 += __shfl_xor(s0, m); s1 += __shfl_xor(s1, m); s2 += __shfl_xor(s2, m);
        }
        if (tx < 3) {
          const float sv = (tx == 0) ? s0 : ((tx == 1) ? s1 : s2);
          s_epi[tx * 272 + (TQ * Qy + i) * 17 + TQ * Qx + j] = sv;
        }
      }
    __syncthreads();
    if (tid < 192) {
      const int o   = tid >> 6;         // wave-uniform (3 waves active)
      const int rem = tid & 63;
      const int row = rem >> 2;
      const int xq  = (rem & 3) << 2;
      const float be = b_ep[o];
      float4 v;
      v.x = s_epi[o * 272 + row * 17 + xq + 0] + be;
      v.y = s_epi[o * 272 + row * 17 + xq + 1] + be;
      v.z = s_epi[o * 272 + row * 17 + xq + 2] + be;
      v.w = s_epi[o * 272 + row * 17 + xq + 3] + be;
      float* op = out + ((size_t)((size_t)n * 3 + o) * Ho + (y0 + row)) * Wo + x0 + xq;
      *reinterpret_cast<float4*>(op) = v;
    }
  }
}

// Sum K-split partials + bias (+lrelu), float4.
__global__ __launch_bounds__(256) void reduce_bias_act_kernel(
    float* __restrict__ dst, const float* __restrict__ part,
    const float* __restrict__ bias, int total4, int HW, int Cout,
    int S, int seg_stride4, int act)
{
  const int i = blockIdx.x * 256 + threadIdx.x;
  if (i >= total4) return;
  const float4* p = (const float4*)part;
  float4 s = p[i];
  for (int k = 1; k < S; k++) {
    const float4 v = p[i + (size_t)k * seg_stride4];
    s.x += v.x; s.y += v.y; s.z += v.z; s.w += v.w;
  }
  const int co = ((i << 2) / HW) % Cout;
  const float b = bias[co];
  s.x += b; s.y += b; s.z += b; s.w += b;
  if (act) { s.x = lrelu_f(s.x); s.y = lrelu_f(s.y); s.z = lrelu_f(s.z); s.w = lrelu_f(s.w); }
  ((float4*)dst)[i] = s;
}

// ---------------------------------------------------------------------------
// Fused: sum K-split partials + bias + BatchNorm(batch stats) + LeakyReLU.
// One block per channel (1024); 512 values/channel = 2 per thread, summed
// over S segments. Replaces reduce+bn pair for the innermost conv.
// ---------------------------------------------------------------------------
__global__ __launch_bounds__(256) void bn_reduce_lrelu_kernel(
    float* __restrict__ dst, const float* __restrict__ part,
    const float* __restrict__ bias, const float* __restrict__ gamma,
    const float* __restrict__ beta, int S, int seg_stride)
{
  const int c = blockIdx.x;
  const int t = threadIdx.x;
  const size_t i0 = (size_t)c * 256 + t;
  const size_t i1 = (size_t)(1024 + c) * 256 + t;
  float v0 = 0.f, v1 = 0.f;
  for (int s = 0; s < S; s++) {
    v0 += part[i0 + (size_t)s * seg_stride];
    v1 += part[i1 + (size_t)s * seg_stride];
  }
  const float b = bias[c];
  v0 += b; v1 += b;
  float s = v0 + v1;
  float q = v0 * v0 + v1 * v1;
  for (int o = 32; o > 0; o >>= 1) { s += __shfl_down(s, o); q += __shfl_down(q, o); }
  __shared__ float sh[8];
  __shared__ float param[2];
  const int wid = t >> 6, lane = t & 63;
  if (lane == 0) { sh[wid] = s; sh[4 + wid] = q; }
  __syncthreads();
  if (t == 0) {
    const float S_ = sh[0] + sh[1] + sh[2] + sh[3];
    const float Q_ = sh[4] + sh[5] + sh[6] + sh[7];
    const float mean = S_ * (1.f / 512.f);
    const float var = Q_ * (1.f / 512.f) - mean * mean;
    const float scale = gamma[c] / sqrtf(var + BN_EPS);
    param[0] = scale;
    param[1] = beta[c] - mean * scale;
  }
  __syncthreads();
  const float sc = param[0], sf = param[1];
  dst[i0] = lrelu_f(v0 * sc + sf);
  dst[i1] = lrelu_f(v1 * sc + sf);
}

extern "C" void kernel_launch(void* const* d_in, const int* in_sizes, int n_in,
                              void* d_out, int out_size, void* d_ws, size_t ws_size,
                              hipStream_t stream)
{
  (void)in_sizes; (void)n_in; (void)out_size; (void)ws_size;
  const float* x     = (const float*)d_in[0];
  const float* w_d0  = (const float*)d_in[1];
  const float* b_d0  = (const float*)d_in[2];
  const float* w_d1  = (const float*)d_in[3];
  const float* b_d1  = (const float*)d_in[4];
  const float* w_d2  = (const float*)d_in[5];
  const float* b_d2  = (const float*)d_in[6];
  const float* w_d3  = (const float*)d_in[7];
  const float* b_d3  = (const float*)d_in[8];
  const float* w_d4  = (const float*)d_in[9];
  const float* b_d4  = (const float*)d_in[10];
  const float* w_in  = (const float*)d_in[11];
  const float* b_in  = (const float*)d_in[12];
  const float* gamma = (const float*)d_in[13];
  const float* beta  = (const float*)d_in[14];
  const float* w_u0  = (const float*)d_in[15];
  const float* b_u0  = (const float*)d_in[16];
  const float* w_u1  = (const float*)d_in[17];
  const float* b_u1  = (const float*)d_in[18];
  const float* w_u2  = (const float*)d_in[19];
  const float* b_u2  = (const float*)d_in[20];
  const float* w_u3  = (const float*)d_in[21];
  const float* b_u3  = (const float*)d_in[22];
  const float* w_u4  = (const float*)d_in[23];
  const float* b_u4  = (const float*)d_in[24];
  const float* w_ep  = (const float*)d_in[25];
  const float* b_ep  = (const float*)d_in[26];

  // ---- 64 MiB workspace map (float offsets; 1 MiB = 262144 floats) ----
  float* W = (float*)d_ws;
  float* e0  = W;                   // [0,32)  d0 out
  float* e1  = W + 8388608;         // [32,48) d1 out
  float* Pd2 = W;                   // [0,16)  2 segs x 8 MiB
  float* e2  = W + 12582912;        // [48,56) d2 out
  float* Pd3 = W;                   // [0,16)  4 segs x 4 MiB
  float* e3  = W + 14680064;        // [56,58) d3 out
  float* Pd4 = W;                   // [0,16)  8 segs x 2 MiB
  float* e4  = W + 15204352;        // [58,60) d4 out
  float* Pin = W;                   // [0,16)  8 segs x 2 MiB
  float* Fb  = W + 15728640;        // [60,62) bn output
  float* Pu0 = W;                   // [0,32)  8 segs x 4 MiB
  float* G   = W + 8388608;         // [32,36) u0 out
  float* Pu1 = W;                   // [0,32)  4 segs x 8 MiB
  float* H   = W + 9437184;         // [36,44) u1 out
  float* Pu2 = W;                   // [0,32)  2 segs x 16 MiB
  float* I   = W + 11534336;        // [44,60) u2 out
  float* J   = W;                   // [0,32)  u3 out
  float* outp = (float*)d_out;

  const dim3 blk(256);
  // -------- encoder (conv+lrelu+down2 fused, 8-wide) --------
  conv3_kernel<1, 4, false><<<dim3(512,   1, 2), blk, 0, stream>>>(x,  w_d0, b_d0, e0,    3, 512, 512,   64, 256, 256, 1,   3,  1, 0);
  conv3_kernel<1, 8, false><<<dim3(128,   2, 2), blk, 0, stream>>>(e0, w_d1, b_d1, e1,   64, 256, 256,  128, 128, 128, 1,  64,  2, 0);
  conv3_kernel<1, 8, true ><<<dim3( 32,   8, 2), blk, 0, stream>>>(e1, w_d2, b_d2, Pd2, 128, 128, 128,  256,  64,  64, 1,  64,  4, 2097152);
  reduce_bias_act_kernel<<<dim3(2048), blk, 0, stream>>>(e2, Pd2, b_d2, 524288, 4096, 256, 2, 524288, 1);
  conv3_kernel<1, 8, true ><<<dim3(  8,  32, 2), blk, 0, stream>>>(e2, w_d3, b_d3, Pd3, 256,  64,  64,  512,  32,  32, 1,  64,  8, 1048576);
  reduce_bias_act_kernel<<<dim3(1024), blk, 0, stream>>>(e3, Pd3, b_d3, 262144, 1024, 512, 4, 262144, 1);
  conv3_kernel<1, 8, true ><<<dim3(  2, 128, 2), blk, 0, stream>>>(e3, w_d4, b_d4, Pd4, 512,  32,  32, 1024,  16,  16, 1,  64, 16, 524288);
  reduce_bias_act_kernel<<<dim3( 512), blk, 0, stream>>>(e4, Pd4, b_d4, 131072, 256, 1024, 8, 131072, 1);
  // -------- innermost conv (no act) + fused reduce+BN+lrelu --------
  conv3_kernel<0, 8, true ><<<dim3(  2, 128, 2), blk, 0, stream>>>(e4, w_in, b_in, Pin, 1024, 16,  16, 1024,  16,  16, 0, 128, 16, 524288);
  bn_reduce_lrelu_kernel<<<dim3(1024), blk, 0, stream>>>(Fb, Pin, b_in, gamma, beta, 8, 524288);
  // -------- decoder (parity-decomposed up2+conv+lrelu, NQ=2) --------
  up_conv_kernel<2, 4, 8, false, true ><<<dim3(  4, 64, 2), blk, 0, stream>>>(Fb, w_u0, b_u0, Pu0, 1024, 16,  16,  512,  32,  32, 128, 8, 1048576, nullptr, nullptr);
  reduce_bias_act_kernel<<<dim3(1024), blk, 0, stream>>>(G, Pu0, b_u0, 262144, 1024, 512, 8, 262144, 1);
  up_conv_kernel<2, 4, 8, false, true ><<<dim3( 16, 16, 2), blk, 0, stream>>>(G,  w_u1, b_u1, Pu1,  512, 32,  32,  256,  64,  64, 128, 4, 2097152, nullptr, nullptr);
  reduce_bias_act_kernel<<<dim3(2048), blk, 0, stream>>>(H, Pu1, b_u1, 524288, 4096, 256, 4, 524288, 1);
  up_conv_kernel<2, 4, 8, false, true ><<<dim3( 64,  4, 2), blk, 0, stream>>>(H,  w_u2, b_u2, Pu2,  256, 64,  64,  128, 128, 128, 128, 2, 4194304, nullptr, nullptr);
  reduce_bias_act_kernel<<<dim3(4096), blk, 0, stream>>>(I, Pu2, b_u2, 1048576, 16384, 128, 2, 1048576, 1);
  up_conv_kernel<2, 4, 8, false, false><<<dim3(256,  1, 2), blk, 0, stream>>>(I,  w_u3, b_u3, J,    128, 128, 128,   64, 256, 256, 128, 1, 0, nullptr, nullptr);
  // -------- u4 + fused 1x1 epilogue -> d_out --------
  up_conv_kernel<2, 4, 8, true,  false><<<dim3(1024, 1, 2), blk, 0, stream>>>(J,  w_u4, b_u4, outp,  64, 256, 256,   64, 512, 512,  64, 1, 0, w_ep, b_ep);
}